// Round 3
// baseline (1374.722 us; speedup 1.0000x reference)
//
#include <hip/hip_runtime.h>

// MAB (gMLP mixing block) — round 7 resubmit (round-2 bench was an infra
// GPUAcquisitionTimeout; no counters produced): K2 E1 GEMM moved to bf16
// MFMA. K2 was 65us/chunk at MfmaUtil=0 / VALUBusy=52% (scalar fp32 GEMM,
// W1 read 4x per chunk). New K2: one block per (n, u/v half): M=128 rows,
// N=192 f, K=64 ci. Wave tile 32r x 192f (mi=2, ni=12) so each wave owns
// complete rows -> LN3 is a 16-lane shfl_xor reduce. W1 staged fp32->bf16
// transposed to LDS Bs[f][ci] (lanes->ci: conflict-free LDS writes). LN2
// register-resident (2 lanes/row). Epilogue: bias+GELU(+LN3 for u) in regs,
// 2B stores (16 fr-lanes = 32B runs, L2 write-combined). W1 read 1x/chunk.
//
// Dims: B=2, H=W=256, C=128, S=16, G=256, N=256, CI=64, F1=384, HF=192.
// Rows R = 1024; chunk RC = 128.
//
//  WP: Wsgu fp32 [c][k][m] -> WT bf16 [c][m][k]; Wp fp32 -> WpT bf16 [o][i]
//  K1: LN1 + [131072x128]x[128x128] MFMA GEMM + GELU -> xin[r][n][ci]
//  per chunk (128 rows):
//   K2: LN2 + per-n E1 MFMA + GELU + LN3(u) -> u_ln[r][n][f], v[r][n][f]
//   T1: u_ln -> uT[c][r][n]
//   K3: per-c SGU [128x256]x[256x256] via mfma_f32_16x16x32_bf16 -> sT[c][r][m]
//   T2: t[r][m][c] = sT[c][r][m] * v[r][m][c]
//   K4: per-n E2 + b2 + xin residual + recon/concat + outer residual (fp32 out)
//
// ws (bf16 elems): xin 16,777,216 | bufA 6,291,456 | bufV 6,291,456 |
// bufB 6,291,456 | WT 12,582,912 | WpT 16,384 => 96,501,760 bytes.

typedef unsigned int uint_t;
typedef unsigned short us_t;
typedef __attribute__((ext_vector_type(8))) short bf16x8;
typedef __attribute__((ext_vector_type(4))) float f32x4;

#define EPSF 1e-3f

__device__ __forceinline__ float b2f(us_t h){ return __uint_as_float(((uint_t)h) << 16); }
__device__ __forceinline__ float lo2f(uint_t u){ return __uint_as_float(u << 16); }
__device__ __forceinline__ float hi2f(uint_t u){ return __uint_as_float(u & 0xFFFF0000u); }
__device__ __forceinline__ us_t f2b(float f){
  uint_t u = __float_as_uint(f);
  uint_t r = (u + 0x7FFFu + ((u >> 16) & 1u)) >> 16;
  return (us_t)r;
}
__device__ __forceinline__ uint_t pack2(float a, float b){
  return (uint_t)f2b(a) | ((uint_t)f2b(b) << 16);
}
__device__ __forceinline__ float gelu_f(float v){
  return 0.5f*v*(1.f + erff(v*0.7071067811865475f));
}

// ---------------------------------------------------------------- WP
// blocks 0..767: Wsgu fp32 [c][k][m] -> WT bf16 [c][m][k]; block = (c, 64-k tile)
// block 768:     Wp fp32 [in][out]   -> WpT bf16 [out][in]
__global__ __launch_bounds__(256) void wprep(const float* __restrict__ Wsgu,
                                             const float* __restrict__ Wp,
                                             us_t* __restrict__ WT,
                                             us_t* __restrict__ WpT){
  __shared__ __align__(16) us_t ls[128*136];   // 34816 B (>= 64*264 used below)
  int t = threadIdx.x;
  if (blockIdx.x == 768){
    #pragma unroll
    for (int i = 0; i < 16; i++){
      int idx = (i*256 + t)*4;                 // 0..16383
      int row = idx >> 7, col = idx & 127;     // row = in, col = out
      float4 w = *(const float4*)(Wp + idx);
      ls[(col+0)*136 + row] = f2b(w.x);
      ls[(col+1)*136 + row] = f2b(w.y);
      ls[(col+2)*136 + row] = f2b(w.z);
      ls[(col+3)*136 + row] = f2b(w.w);
    }
    __syncthreads();
    #pragma unroll
    for (int i = 0; i < 8; i++){
      int chunk = i*256 + t;                   // 0..2047
      int o = chunk >> 4, i0 = (chunk & 15) << 3;
      *(uint4*)(WpT + o*128 + i0) = *(const uint4*)&ls[o*136 + i0];
    }
    return;
  }
  int c = blockIdx.x >> 2, kt = blockIdx.x & 3;
  const float* src = Wsgu + ((size_t)c*256 + kt*64)*256;
  #pragma unroll
  for (int i = 0; i < 16; i++){
    int chunk = i*256 + t;
    int kk = chunk >> 6, mm = (chunk & 63) << 2;
    float4 w = *(const float4*)(src + kk*256 + mm);
    *(uint2*)&ls[kk*264 + mm] = make_uint2(pack2(w.x,w.y), pack2(w.z,w.w));
  }
  __syncthreads();
  #pragma unroll
  for (int i = 0; i < 8; i++){
    int chunk = i*256 + t;
    int m = chunk >> 3, kk0 = (chunk & 7) << 3;
    const us_t* sp = &ls[kk0*264 + m];
    uint4 o;
    o.x = (uint_t)sp[0]     | ((uint_t)sp[264]   << 16);
    o.y = (uint_t)sp[2*264] | ((uint_t)sp[3*264] << 16);
    o.z = (uint_t)sp[4*264] | ((uint_t)sp[5*264] << 16);
    o.w = (uint_t)sp[6*264] | ((uint_t)sp[7*264] << 16);
    *(uint4*)(WT + ((size_t)c*256 + m)*256 + kt*64 + kk0) = o;
  }
}

// ---------------------------------------------------------------- K1 (MFMA)
// 128 pixels x 128 out-ch per block; K=128 single pass.
__global__ __launch_bounds__(256) void k1_ln_proj(
    const float* __restrict__ x, const float* __restrict__ g1, const float* __restrict__ b1l,
    const us_t* __restrict__ WpT, const float* __restrict__ bp, us_t* __restrict__ xin)
{
  __shared__ __align__(16) us_t As[128*136];
  __shared__ __align__(16) us_t Ws[128*136];
  __shared__ float gs[128], bs[128];
  int t = threadIdx.x;
  int p0 = blockIdx.x * 128;
  int lane = t & 63, wv = t >> 6;

  if (t < 128){ gs[t] = g1[t]; bs[t] = b1l[t]; }
  #pragma unroll
  for (int i = 0; i < 8; i++){                 // stage WpT -> Ws
    int chunk = i*256 + t;
    int row = chunk >> 4, k0 = (chunk & 15) << 3;
    *(uint4*)&Ws[row*136 + k0] = *(const uint4*)(WpT + row*128 + k0);
  }
  // LN1: 2 lanes per pixel, 64 channels each, register-resident
  int pl = t >> 1, half = t & 1;
  const float* xr = x + (size_t)(p0 + pl)*128 + half*64;
  float xv[64];
  float s = 0.f, q = 0.f;
  #pragma unroll
  for (int i = 0; i < 16; i++){
    float4 d = *(const float4*)(xr + i*4);
    xv[i*4+0] = d.x; xv[i*4+1] = d.y; xv[i*4+2] = d.z; xv[i*4+3] = d.w;
    s += d.x + d.y + d.z + d.w;
    q += d.x*d.x + d.y*d.y + d.z*d.z + d.w*d.w;
  }
  s += __shfl_xor(s, 1, 64);
  q += __shfl_xor(q, 1, 64);
  float m = s*(1.f/128.f);
  float rstd = rsqrtf(q*(1.f/128.f) - m*m + EPSF);
  __syncthreads();                             // gs/bs (and Ws) visible
  {
    int c0 = half << 6;
    us_t* dst = &As[pl*136 + c0];
    #pragma unroll
    for (int jj = 0; jj < 8; jj++){
      float y[8];
      #pragma unroll
      for (int k = 0; k < 8; k++){
        int idx = jj*8 + k;
        y[k] = (xv[idx] - m)*rstd*gs[c0 + idx] + bs[c0 + idx];
      }
      uint4 o;
      o.x = pack2(y[0], y[1]);
      o.y = pack2(y[2], y[3]);
      o.z = pack2(y[4], y[5]);
      o.w = pack2(y[6], y[7]);
      *(uint4*)&dst[jj*8] = o;
    }
  }
  __syncthreads();
  int wm0 = (wv >> 1) * 64, wn0 = (wv & 1) * 64;
  int fr = lane & 15, fq = lane >> 4;
  f32x4 acc[4][4] = {};                        // [mi=ch frag][ni=pix frag]
  #pragma unroll
  for (int sstep = 0; sstep < 4; sstep++){
    int kb = sstep*32 + fq*8;
    bf16x8 a[4], b[4];
    #pragma unroll
    for (int mi = 0; mi < 4; mi++)
      a[mi] = *(const bf16x8*)&Ws[(wm0 + mi*16 + fr)*136 + kb];
    #pragma unroll
    for (int ni = 0; ni < 4; ni++)
      b[ni] = *(const bf16x8*)&As[(wn0 + ni*16 + fr)*136 + kb];
    #pragma unroll
    for (int mi = 0; mi < 4; mi++)
      #pragma unroll
      for (int ni = 0; ni < 4; ni++)
        acc[mi][ni] = __builtin_amdgcn_mfma_f32_16x16x32_bf16(a[mi], b[ni], acc[mi][ni], 0, 0, 0);
  }
  // epilogue: bias + GELU + scatter to xin (4 consecutive channels per lane)
  #pragma unroll
  for (int mi = 0; mi < 4; mi++){
    int ch0 = wm0 + mi*16 + fq*4;
    float4 bb = *(const float4*)(bp + ch0);
    int branch = ch0 >> 6, c = ch0 & 63;
    #pragma unroll
    for (int ni = 0; ni < 4; ni++){
      int p = p0 + wn0 + ni*16 + fr;
      int b_ = p >> 16, rem = p & 65535, h = rem >> 8, w = rem & 255;
      int g = ((h >> 4) << 4) | (w >> 4);
      int nn = ((h & 15) << 4) | (w & 15);
      float v0 = gelu_f(acc[mi][ni][0] + bb.x);
      float v1 = gelu_f(acc[mi][ni][1] + bb.y);
      float v2 = gelu_f(acc[mi][ni][2] + bb.z);
      float v3 = gelu_f(acc[mi][ni][3] + bb.w);
      size_t row = (size_t)branch*512 + (size_t)b_*256 + g;
      *(uint2*)(xin + (row*256 + nn)*64 + c) = make_uint2(pack2(v0,v1), pack2(v2,v3));
    }
  }
}

// ---------------------------------------------------------------- K2 (chunk RC=128, MFMA)
// grid = 512: n = bid>>1, uv = bid&1 (0 = u half f0..191, 1 = v half f192..383)
// Per block: [128 rows x 64 ci] x [64 ci x 192 f] bf16 MFMA.
// Wave tile 32 rows x 192 f: mi=0..1 (16-row frags), ni=0..11 (16-f frags).
__global__ __launch_bounds__(256) void k2_e1(
    const us_t* __restrict__ xin,
    const float* __restrict__ g2, const float* __restrict__ b2l,
    const float* __restrict__ W1, const float* __restrict__ b1v,
    const float* __restrict__ g3, const float* __restrict__ b3l,
    us_t* __restrict__ u_ln, us_t* __restrict__ vout, int r_base)
{
  __shared__ __align__(16) us_t Bs[192*72];   // W1T half: [f][ci]
  __shared__ __align__(16) us_t As[128*72];   // LN2(x):  [r][ci]
  __shared__ __align__(16) float b1s[192];
  __shared__ __align__(16) float g3s[192];
  __shared__ __align__(16) float b3s[192];
  __shared__ __align__(16) float g2s[64];
  __shared__ __align__(16) float b2s[64];
  int t = threadIdx.x;
  int n = blockIdx.x >> 1, uv = blockIdx.x & 1;
  int lane = t & 63, wv = t >> 6;
  int fr = lane & 15, fq = lane >> 4;

  // ---- stage W1 half transposed -> Bs[f][ci]; lanes map to ci so the
  // 2B LDS writes are contiguous (conflict-free); global reads stride 1536B
  // but all lines are consumed within the staging loop (L1/L2 resident).
  const float* wsrc = W1 + (size_t)n*24576 + uv*192;
  #pragma unroll
  for (int i = 0; i < 12; i++){
    int chunk = i*256 + t;
    int ci = chunk & 63, fb = chunk >> 6;      // fb = 0..47 (4 f each)
    float4 w = *(const float4*)(wsrc + ci*384 + fb*4);
    us_t* dst = &Bs[(fb*4)*72 + ci];
    dst[0]   = f2b(w.x);
    dst[72]  = f2b(w.y);
    dst[144] = f2b(w.z);
    dst[216] = f2b(w.w);
  }
  if (t < 48)        *(float4*)&b1s[t*4]       = *(const float4*)(b1v + n*384 + uv*192 + t*4);
  else if (t < 96)   *(float4*)&g3s[(t-48)*4]  = *(const float4*)(g3  + (t-48)*4);
  else if (t < 144)  *(float4*)&b3s[(t-96)*4]  = *(const float4*)(b3l + (t-96)*4);
  else if (t < 160)  *(float4*)&g2s[(t-144)*4] = *(const float4*)(g2  + (t-144)*4);
  else if (t < 176)  *(float4*)&b2s[(t-160)*4] = *(const float4*)(b2l + (t-160)*4);

  // ---- LN2: 2 lanes/row, 32 ch each, register-resident
  int rr = t >> 1, half = t & 1;
  const us_t* xsrc = xin + ((size_t)(r_base + rr)*256 + n)*64 + half*32;
  uint4 d0 = *(const uint4*)(xsrc);
  uint4 d1 = *(const uint4*)(xsrc + 8);
  uint4 d2 = *(const uint4*)(xsrc + 16);
  uint4 d3 = *(const uint4*)(xsrc + 24);
  float xv[32];
  {
    uint4 dd[4] = {d0, d1, d2, d3};
    #pragma unroll
    for (int j = 0; j < 4; j++){
      xv[j*8+0]=lo2f(dd[j].x); xv[j*8+1]=hi2f(dd[j].x);
      xv[j*8+2]=lo2f(dd[j].y); xv[j*8+3]=hi2f(dd[j].y);
      xv[j*8+4]=lo2f(dd[j].z); xv[j*8+5]=hi2f(dd[j].z);
      xv[j*8+6]=lo2f(dd[j].w); xv[j*8+7]=hi2f(dd[j].w);
    }
  }
  float s = 0.f, q = 0.f;
  #pragma unroll
  for (int j = 0; j < 32; j++){ s += xv[j]; q += xv[j]*xv[j]; }
  s += __shfl_xor(s, 1, 64);
  q += __shfl_xor(q, 1, 64);
  float m = s*(1.f/64.f);
  float rstd = rsqrtf(q*(1.f/64.f) - m*m + EPSF);
  __syncthreads();                             // g2s/b2s ready; Bs complete
  {
    int cb = half*32;
    us_t* dst = &As[rr*72 + cb];
    #pragma unroll
    for (int jj = 0; jj < 4; jj++){
      float y[8];
      #pragma unroll
      for (int k = 0; k < 8; k++){
        int idx = cb + jj*8 + k;
        y[k] = (xv[jj*8+k] - m)*rstd*g2s[idx] + b2s[idx];
      }
      uint4 o;
      o.x = pack2(y[0], y[1]);
      o.y = pack2(y[2], y[3]);
      o.z = pack2(y[4], y[5]);
      o.w = pack2(y[6], y[7]);
      *(uint4*)&dst[jj*8] = o;
    }
  }
  __syncthreads();                             // As complete

  // ---- MFMA: wave tile 32 rows x 192 f; K=64 in two 32-steps
  int wr0 = wv*32;
  f32x4 acc[2][12] = {};
  #pragma unroll
  for (int ks = 0; ks < 2; ks++){
    int kb = ks*32 + fq*8;
    bf16x8 a0 = *(const bf16x8*)&As[(wr0 + fr)*72 + kb];
    bf16x8 a1 = *(const bf16x8*)&As[(wr0 + 16 + fr)*72 + kb];
    #pragma unroll
    for (int ni = 0; ni < 12; ni++){
      bf16x8 b = *(const bf16x8*)&Bs[(ni*16 + fr)*72 + kb];
      acc[0][ni] = __builtin_amdgcn_mfma_f32_16x16x32_bf16(a0, b, acc[0][ni], 0, 0, 0);
      acc[1][ni] = __builtin_amdgcn_mfma_f32_16x16x32_bf16(a1, b, acc[1][ni], 0, 0, 0);
    }
  }

  // ---- epilogue: bias + GELU (+ LN3 for u). D row = wr0+mi*16+fq*4+i,
  // col f = ni*16+fr. 16 fr-lanes give 32B-contiguous 2B stores.
  float bsv[12];
  #pragma unroll
  for (int ni = 0; ni < 12; ni++) bsv[ni] = b1s[ni*16 + fr];
  if (uv == 0){
    float g3v[12], b3v[12];
    #pragma unroll
    for (int ni = 0; ni < 12; ni++){ g3v[ni] = g3s[ni*16+fr]; b3v[ni] = b3s[ni*16+fr]; }
    #pragma unroll
    for (int mi = 0; mi < 2; mi++){
      #pragma unroll
      for (int i = 0; i < 4; i++){
        int r = wr0 + mi*16 + fq*4 + i;
        float y[12];
        float ss = 0.f, qq = 0.f;
        #pragma unroll
        for (int ni = 0; ni < 12; ni++){
          float yv = gelu_f(acc[mi][ni][i] + bsv[ni]);
          y[ni] = yv; ss += yv; qq += yv*yv;
        }
        #pragma unroll
        for (int off = 8; off; off >>= 1){ ss += __shfl_xor(ss, off, 64); qq += __shfl_xor(qq, off, 64); }
        float mm = ss*(1.f/192.f);
        float rs = rsqrtf(qq*(1.f/192.f) - mm*mm + EPSF);
        us_t* dst = u_ln + ((size_t)r*256 + n)*192 + fr;
        #pragma unroll
        for (int ni = 0; ni < 12; ni++)
          dst[ni*16] = f2b((y[ni]-mm)*rs*g3v[ni] + b3v[ni]);
      }
    }
  } else {
    #pragma unroll
    for (int mi = 0; mi < 2; mi++){
      #pragma unroll
      for (int i = 0; i < 4; i++){
        int r = wr0 + mi*16 + fq*4 + i;
        us_t* dst = vout + ((size_t)r*256 + n)*192 + fr;
        #pragma unroll
        for (int ni = 0; ni < 12; ni++)
          dst[ni*16] = f2b(gelu_f(acc[mi][ni][i] + bsv[ni]));
      }
    }
  }
}

// ---------------------------------------------------------------- T1 (RC=128)
// u_ln[r][n][c] -> uT[c][r][n], r in [0,128); grid = 128 r x 2 n-halves
__global__ __launch_bounds__(256) void t1_transpose(const us_t* __restrict__ u_ln, us_t* __restrict__ uT){
  __shared__ us_t ls[128*194];
  int t = threadIdx.x;
  int r = blockIdx.x >> 1, n0 = (blockIdx.x & 1) << 7;
  #pragma unroll
  for (int i = 0; i < 12; i++){
    int chunk = i*256 + t;
    int nn = chunk/24, c0 = (chunk - nn*24)*8;
    uint4 d = *(const uint4*)(u_ln + ((size_t)r*256 + n0 + nn)*192 + c0);
    us_t* dst = &ls[nn*194 + c0];
    dst[0] = (us_t)d.x; dst[1] = (us_t)(d.x>>16);
    dst[2] = (us_t)d.y; dst[3] = (us_t)(d.y>>16);
    dst[4] = (us_t)d.z; dst[5] = (us_t)(d.z>>16);
    dst[6] = (us_t)d.w; dst[7] = (us_t)(d.w>>16);
  }
  __syncthreads();
  #pragma unroll
  for (int i = 0; i < 12; i++){
    int chunk = i*256 + t;
    int c = chunk >> 4, nn0 = (chunk & 15) << 3;
    const us_t* sp = &ls[nn0*194 + c];
    uint4 o;
    o.x = (uint_t)sp[0]     | ((uint_t)sp[194]   << 16);
    o.y = (uint_t)sp[2*194] | ((uint_t)sp[3*194] << 16);
    o.z = (uint_t)sp[4*194] | ((uint_t)sp[5*194] << 16);
    o.w = (uint_t)sp[6*194] | ((uint_t)sp[7*194] << 16);
    *(uint4*)(uT + ((size_t)c*128 + r)*256 + n0 + nn0) = o;
  }
}

// ---------------------------------------------------------------- K3 (RC=128, MFMA)
// per-c SGU: S[r][m] = sum_k U[r][k] W[k][m]; 128x256x256 per c, bf16 MFMA.
// grid = 192 c x 2 mt; block tile 128r x 128m; wave = 64x64; BK=64.
__global__ __launch_bounds__(256) void k3_sgu_mfma(
    const us_t* __restrict__ uT, const us_t* __restrict__ WT,
    const float* __restrict__ bsgu, us_t* __restrict__ sT)
{
  __shared__ __align__(16) us_t As[128*72];
  __shared__ __align__(16) us_t Bs[128*72];
  int t = threadIdx.x;
  int c = blockIdx.x >> 1, mt = blockIdx.x & 1;
  int lane = t & 63, wv = t >> 6;
  int wr0 = (wv >> 1) * 64, wm0 = (wv & 1) * 64;
  int fr = lane & 15, fq = lane >> 4;          // frag row / k-quad
  f32x4 acc[4][4] = {};                         // [mi][ni]

  const us_t* aSrc = uT + (size_t)c*128*256;
  const us_t* bSrc = WT + ((size_t)(c*256 + mt*128))*256;

  for (int ks = 0; ks < 256; ks += 64){
    #pragma unroll
    for (int i = 0; i < 4; i++){               // 128 rows x 64 k per array
      int chunk = i*256 + t;
      int rr = chunk >> 3, kk = (chunk & 7) << 3;
      *(uint4*)&As[rr*72 + kk] = *(const uint4*)(aSrc + rr*256 + ks + kk);
      *(uint4*)&Bs[rr*72 + kk] = *(const uint4*)(bSrc + rr*256 + ks + kk);
    }
    __syncthreads();
    #pragma unroll
    for (int s = 0; s < 2; s++){
      int kb = s*32 + fq*8;
      bf16x8 a[4], b[4];
      #pragma unroll
      for (int mi = 0; mi < 4; mi++)
        a[mi] = *(const bf16x8*)&As[(wr0 + mi*16 + fr)*72 + kb];
      #pragma unroll
      for (int ni = 0; ni < 4; ni++)
        b[ni] = *(const bf16x8*)&Bs[(wm0 + ni*16 + fr)*72 + kb];
      #pragma unroll
      for (int mi = 0; mi < 4; mi++)
        #pragma unroll
        for (int ni = 0; ni < 4; ni++)
          acc[mi][ni] = __builtin_amdgcn_mfma_f32_16x16x32_bf16(a[mi], b[ni], acc[mi][ni], 0, 0, 0);
    }
    __syncthreads();
  }
  // epilogue: D[row=wr0+mi*16+fq*4+i][col=wm0+ni*16+fr] + bsgu[c][m]
  float bsv[4];
  #pragma unroll
  for (int ni = 0; ni < 4; ni++)
    bsv[ni] = bsgu[c*256 + mt*128 + wm0 + ni*16 + fr];
  #pragma unroll
  for (int mi = 0; mi < 4; mi++){
    #pragma unroll
    for (int i = 0; i < 4; i++){
      int r = wr0 + mi*16 + fq*4 + i;          // 0..127
      us_t* dst = sT + ((size_t)c*128 + r)*256 + mt*128 + wm0 + fr;
      #pragma unroll
      for (int ni = 0; ni < 4; ni++)
        dst[ni*16] = f2b(acc[mi][ni][i] + bsv[ni]);
    }
  }
}

// ---------------------------------------------------------------- T2 (RC=128)
// t[r][m][c] = sT[c][r][m] * v[r][m][c], r in [0,128)
__global__ __launch_bounds__(256) void t2_mul(
    const us_t* __restrict__ sT, const us_t* __restrict__ v, us_t* __restrict__ tout)
{
  __shared__ us_t ls[192*130];
  int t = threadIdx.x;
  int r = blockIdx.x >> 1, m0 = (blockIdx.x & 1) << 7;
  #pragma unroll
  for (int i = 0; i < 12; i++){
    int chunk = i*256 + t;
    int c = chunk >> 4, mm0 = (chunk & 15) << 3;
    uint4 d = *(const uint4*)(sT + ((size_t)c*128 + r)*256 + m0 + mm0);
    us_t* dst = &ls[c*130 + mm0];
    dst[0] = (us_t)d.x; dst[1] = (us_t)(d.x>>16);
    dst[2] = (us_t)d.y; dst[3] = (us_t)(d.y>>16);
    dst[4] = (us_t)d.z; dst[5] = (us_t)(d.z>>16);
    dst[6] = (us_t)d.w; dst[7] = (us_t)(d.w>>16);
  }
  __syncthreads();
  #pragma unroll
  for (int i = 0; i < 12; i++){
    int chunk = i*256 + t;
    int mm = chunk/24, c0 = (chunk - mm*24)*8;
    size_t gidx = ((size_t)r*256 + m0 + mm)*192 + c0;
    uint4 vv = *(const uint4*)(v + gidx);
    const us_t* sp = &ls[c0*130 + mm];
    uint4 o;
    o.x = pack2(b2f(sp[0])*lo2f(vv.x),     b2f(sp[130])*hi2f(vv.x));
    o.y = pack2(b2f(sp[2*130])*lo2f(vv.y), b2f(sp[3*130])*hi2f(vv.y));
    o.z = pack2(b2f(sp[4*130])*lo2f(vv.z), b2f(sp[5*130])*hi2f(vv.z));
    o.w = pack2(b2f(sp[6*130])*lo2f(vv.w), b2f(sp[7*130])*hi2f(vv.w));
    *(uint4*)(tout + gidx) = o;
  }
}

// ---------------------------------------------------------------- K4 (RC=128)
// grid = 256 n x 2 rt
__global__ __launch_bounds__(256) void k4_out(
    const us_t* __restrict__ tbuf, const float* __restrict__ W2,
    const float* __restrict__ b2v, const us_t* __restrict__ xin,
    const float* __restrict__ x, float* __restrict__ out0, float* __restrict__ out1,
    int r_base)
{
  __shared__ __align__(16) us_t W2s[192*64];
  __shared__ __align__(16) us_t ts[192*68];   // [f][row]
  int t = threadIdx.x;
  int n = blockIdx.x >> 1, rt = blockIdx.x & 1;
  const float* wsrc = W2 + (size_t)n*12288;
  #pragma unroll
  for (int i = 0; i < 12; i++){   // W2 fp32 -> bf16 LDS
    int idx = (i*256 + t)*4;
    float4 w = *(const float4*)(wsrc + idx);
    *(uint2*)&W2s[idx] = make_uint2(pack2(w.x,w.y), pack2(w.z,w.w));
  }
  #pragma unroll
  for (int i = 0; i < 6; i++){
    int chunk = i*256 + t;
    int rr = chunk/24, ff0 = (chunk - rr*24)*8;
    uint4 d = *(const uint4*)(tbuf + ((size_t)(rt*64 + rr)*256 + n)*192 + ff0);
    us_t* dst = &ts[ff0*68 + rr];
    dst[0]    = (us_t)d.x; dst[68]   = (us_t)(d.x>>16);
    dst[2*68] = (us_t)d.y; dst[3*68] = (us_t)(d.y>>16);
    dst[4*68] = (us_t)d.z; dst[5*68] = (us_t)(d.z>>16);
    dst[6*68] = (us_t)d.w; dst[7*68] = (us_t)(d.w>>16);
  }
  __syncthreads();
  int cg = t & 15, rg = t >> 4;
  int c0 = cg*4, rr0 = rg*4;
  float acc[4][4] = {};
  #pragma unroll 4
  for (int f = 0; f < 192; f++){
    uint2 au = *(const uint2*)&ts[f*68 + rr0];
    uint2 wu = *(const uint2*)&W2s[f*64 + c0];
    float a0 = lo2f(au.x), a1 = hi2f(au.x), a2 = lo2f(au.y), a3 = hi2f(au.y);
    float w0 = lo2f(wu.x), w1 = hi2f(wu.x), w2 = lo2f(wu.y), w3 = hi2f(wu.y);
    acc[0][0] += a0*w0; acc[0][1] += a0*w1; acc[0][2] += a0*w2; acc[0][3] += a0*w3;
    acc[1][0] += a1*w0; acc[1][1] += a1*w1; acc[1][2] += a1*w2; acc[1][3] += a1*w3;
    acc[2][0] += a2*w0; acc[2][1] += a2*w1; acc[2][2] += a2*w2; acc[2][3] += a2*w3;
    acc[3][0] += a3*w0; acc[3][1] += a3*w1; acc[3][2] += a3*w2; acc[3][3] += a3*w3;
  }
  float4 bb = *(const float4*)(b2v + n*64 + c0);
  #pragma unroll
  for (int i = 0; i < 4; i++){
    int rl = rt*64 + rr0 + i;                  // chunk-local 0..127
    int r = r_base + rl;                       // global row
    int branch = r >> 9, bidx = (r >> 8) & 1, g = r & 255;
    uint2 xi = *(const uint2*)(xin + ((size_t)r*256 + n)*64 + c0);
    float v0 = acc[i][0] + bb.x + lo2f(xi.x);
    float v1 = acc[i][1] + bb.y + hi2f(xi.x);
    float v2 = acc[i][2] + bb.z + lo2f(xi.y);
    float v3 = acc[i][3] + bb.w + hi2f(xi.y);
    int h, w;
    if (branch == 0){ h = ((n >> 4) << 4) | (g >> 4); w = ((n & 15) << 4) | (g & 15); }
    else            { h = ((g >> 4) << 4) | (n >> 4); w = ((g & 15) << 4) | (n & 15); }
    size_t base = (size_t)(bidx*256 + h)*256 + w;
    size_t o0idx = base*128 + (branch << 6) + c0;
    float4 xr = *(const float4*)(x + o0idx);
    *(float4*)(out0 + o0idx) = make_float4(v0 + xr.x, v1 + xr.y, v2 + xr.z, v3 + xr.w);
    if (branch){
      *(float4*)(out1 + base*64 + c0) = make_float4(v0, v1, v2, v3);
    }
  }
}

// ---------------------------------------------------------------- launch
extern "C" void kernel_launch(void* const* d_in, const int* in_sizes, int n_in,
                              void* d_out, int out_size, void* d_ws, size_t ws_size,
                              hipStream_t stream)
{
  (void)in_sizes; (void)n_in; (void)out_size; (void)ws_size;
  const float* x    = (const float*)d_in[0];
  const float* g1   = (const float*)d_in[1];
  const float* b1l  = (const float*)d_in[2];
  const float* Wp   = (const float*)d_in[3];
  const float* bp   = (const float*)d_in[4];
  const float* g2   = (const float*)d_in[5];
  const float* b2l  = (const float*)d_in[6];
  const float* W1   = (const float*)d_in[7];
  const float* b1v  = (const float*)d_in[8];
  const float* g3   = (const float*)d_in[9];
  const float* b3l  = (const float*)d_in[10];
  const float* Wsgu = (const float*)d_in[11];
  const float* bsgu = (const float*)d_in[12];
  const float* W2   = (const float*)d_in[13];
  const float* b2v  = (const float*)d_in[14];

  float* out0 = (float*)d_out;
  float* out1 = out0 + (size_t)2*256*256*128;

  us_t* ws   = (us_t*)d_ws;
  us_t* xin  = ws;                       // [1024][256][64]        16,777,216
  us_t* bufA = ws + 16777216;            // u_ln -> sT (chunk)      6,291,456
  us_t* bufV = bufA + 6291456;           // v (chunk)               6,291,456
  us_t* bufB = bufV + 6291456;           // uT -> t (chunk)         6,291,456
  us_t* WT   = bufB + 6291456;           // Wsgu^T bf16 [c][m][k]  12,582,912
  us_t* WpT  = WT + 12582912;            // Wp^T bf16 [out][in]        16,384

  wprep      <<<dim3(769),  dim3(256), 0, stream>>>(Wsgu, Wp, WT, WpT);
  k1_ln_proj <<<dim3(1024), dim3(256), 0, stream>>>(x, g1, b1l, WpT, bp, xin);
  for (int chunk = 0; chunk < 8; ++chunk){
    int r_base = chunk * 128;
    k2_e1       <<<dim3(512),  dim3(256), 0, stream>>>(xin, g2, b2l, W1, b1v, g3, b3l, bufA, bufV, r_base);
    t1_transpose<<<dim3(256),  dim3(256), 0, stream>>>(bufA, bufB);
    k3_sgu_mfma <<<dim3(384),  dim3(256), 0, stream>>>(bufB, WT, bsgu, bufA);
    t2_mul      <<<dim3(256),  dim3(256), 0, stream>>>(bufA, bufV, bufB);
    k4_out      <<<dim3(512),  dim3(256), 0, stream>>>(bufB, W2, b2v, xin, x, out0, out1, r_base);
  }
}

// Round 6
// 1049.744 us; speedup vs baseline: 1.3096x; 1.3096x over previous
//
#include <hip/hip_runtime.h>

// MAB (gMLP mixing block) — round 9: controlled experiment isolating the
// round-8 correctness failure (absmax 0.864). Round 8 bundled (a) w1t
// pre-transpose, (b) full K2 restructure, (c) ws placement switch — one of
// them broke numerics. This round: K2 reverted VERBATIM to the round-3
// structure (passed, absmax 0.117; 512 blocks, 128-row tile, 2-lane LN2,
// two barriers) with ONLY the Bs staging changed: coalesced uint4 reads
// from W1T bf16 [n][384f][64ci] (w1t kernel) instead of the 1536B-stride
// scatter that made round-3 k2 latency-bound (135us @ 1.6% HBM, 11% occ).
// Bs bytes are identical-by-construction to round 3 => pass proves w1t,
// fail isolates w1t. Perf: staging storm was the 135us; expect k2 ~28us.
//
// Dims: B=2, H=W=256, C=128, S=16, G=256, N=256, CI=64, F1=384, HF=192.
// Rows R = 1024; chunk RC = 128.
//
//  WP: Wsgu fp32 [c][k][m] -> WT bf16 [c][m][k]; Wp fp32 -> WpT bf16 [o][i]
//  W1T: W1 fp32 [n][ci][f] -> bf16 [n][f][ci]
//  K1: LN1 + [131072x128]x[128x128] MFMA GEMM + GELU -> xin[r][n][ci]
//  per chunk (128 rows):
//   K2: LN2 + per-n E1 MFMA + GELU + LN3(u) -> u_ln[r][n][f], v[r][n][f]
//   T1: u_ln -> uT[c][r][n]
//   K3: per-c SGU [128x256]x[256x256] via mfma_f32_16x16x32_bf16 -> sT[c][r][m]
//   T2: t[r][m][c] = sT[c][r][m] * v[r][m][c]
//   K4: per-n E2 + b2 + xin residual + recon/concat + outer residual (fp32 out)
//
// ws (bf16 elems): xin 16,777,216 | bufA 6,291,456 | bufV 6,291,456 |
// bufB 6,291,456 | WT 12,582,912 | WpT 16,384 [| W1T 6,291,456 if room]
//  => 96,501,760 B base, 109,084,672 B with dedicated W1T (else W1T lives
//  in bufB, dead at k2-time, and w1t reruns per chunk ~6us).

typedef unsigned int uint_t;
typedef unsigned short us_t;
typedef __attribute__((ext_vector_type(8))) short bf16x8;
typedef __attribute__((ext_vector_type(4))) float f32x4;

#define EPSF 1e-3f

__device__ __forceinline__ float b2f(us_t h){ return __uint_as_float(((uint_t)h) << 16); }
__device__ __forceinline__ float lo2f(uint_t u){ return __uint_as_float(u << 16); }
__device__ __forceinline__ float hi2f(uint_t u){ return __uint_as_float(u & 0xFFFF0000u); }
__device__ __forceinline__ us_t f2b(float f){
  uint_t u = __float_as_uint(f);
  uint_t r = (u + 0x7FFFu + ((u >> 16) & 1u)) >> 16;
  return (us_t)r;
}
__device__ __forceinline__ uint_t pack2(float a, float b){
  return (uint_t)f2b(a) | ((uint_t)f2b(b) << 16);
}
__device__ __forceinline__ float gelu_f(float v){
  return 0.5f*v*(1.f + erff(v*0.7071067811865475f));
}

// ---------------------------------------------------------------- WP
// blocks 0..767: Wsgu fp32 [c][k][m] -> WT bf16 [c][m][k]; block = (c, 64-k tile)
// block 768:     Wp fp32 [in][out]   -> WpT bf16 [out][in]
__global__ __launch_bounds__(256) void wprep(const float* __restrict__ Wsgu,
                                             const float* __restrict__ Wp,
                                             us_t* __restrict__ WT,
                                             us_t* __restrict__ WpT){
  __shared__ __align__(16) us_t ls[128*136];   // 34816 B (>= 64*264 used below)
  int t = threadIdx.x;
  if (blockIdx.x == 768){
    #pragma unroll
    for (int i = 0; i < 16; i++){
      int idx = (i*256 + t)*4;                 // 0..16383
      int row = idx >> 7, col = idx & 127;     // row = in, col = out
      float4 w = *(const float4*)(Wp + idx);
      ls[(col+0)*136 + row] = f2b(w.x);
      ls[(col+1)*136 + row] = f2b(w.y);
      ls[(col+2)*136 + row] = f2b(w.z);
      ls[(col+3)*136 + row] = f2b(w.w);
    }
    __syncthreads();
    #pragma unroll
    for (int i = 0; i < 8; i++){
      int chunk = i*256 + t;                   // 0..2047
      int o = chunk >> 4, i0 = (chunk & 15) << 3;
      *(uint4*)(WpT + o*128 + i0) = *(const uint4*)&ls[o*136 + i0];
    }
    return;
  }
  int c = blockIdx.x >> 2, kt = blockIdx.x & 3;
  const float* src = Wsgu + ((size_t)c*256 + kt*64)*256;
  #pragma unroll
  for (int i = 0; i < 16; i++){
    int chunk = i*256 + t;
    int kk = chunk >> 6, mm = (chunk & 63) << 2;
    float4 w = *(const float4*)(src + kk*256 + mm);
    *(uint2*)&ls[kk*264 + mm] = make_uint2(pack2(w.x,w.y), pack2(w.z,w.w));
  }
  __syncthreads();
  #pragma unroll
  for (int i = 0; i < 8; i++){
    int chunk = i*256 + t;
    int m = chunk >> 3, kk0 = (chunk & 7) << 3;
    const us_t* sp = &ls[kk0*264 + m];
    uint4 o;
    o.x = (uint_t)sp[0]     | ((uint_t)sp[264]   << 16);
    o.y = (uint_t)sp[2*264] | ((uint_t)sp[3*264] << 16);
    o.z = (uint_t)sp[4*264] | ((uint_t)sp[5*264] << 16);
    o.w = (uint_t)sp[6*264] | ((uint_t)sp[7*264] << 16);
    *(uint4*)(WT + ((size_t)c*256 + m)*256 + kt*64 + kk0) = o;
  }
}

// ---------------------------------------------------------------- W1T
// W1 fp32 [n][64ci][384f] -> W1T bf16 [n][384f][64ci]; grid = 256 (per n)
__global__ __launch_bounds__(256) void w1t(const float* __restrict__ W1,
                                           us_t* __restrict__ W1T){
  __shared__ __align__(16) us_t ls[64*392];    // [ci][f], pad 392 (50176 B)
  int t = threadIdx.x;
  const float* src = W1 + (size_t)blockIdx.x * 24576;
  #pragma unroll
  for (int i = 0; i < 24; i++){
    int idx = (i*256 + t)*4;                   // 0..24575, coalesced float4
    int ci = idx / 384, f = idx - ci*384;      // f % 4 == 0
    float4 w = *(const float4*)(src + idx);
    *(uint2*)&ls[ci*392 + f] = make_uint2(pack2(w.x,w.y), pack2(w.z,w.w));
  }
  __syncthreads();
  us_t* dstb = W1T + (size_t)blockIdx.x * 24576;
  #pragma unroll
  for (int i = 0; i < 12; i++){
    int chunk = i*256 + t;                     // 0..3071
    int f = chunk >> 3, ci0 = (chunk & 7) << 3;
    const us_t* sp = &ls[ci0*392 + f];
    uint4 o;
    o.x = (uint_t)sp[0]     | ((uint_t)sp[392]   << 16);
    o.y = (uint_t)sp[2*392] | ((uint_t)sp[3*392] << 16);
    o.z = (uint_t)sp[4*392] | ((uint_t)sp[5*392] << 16);
    o.w = (uint_t)sp[6*392] | ((uint_t)sp[7*392] << 16);
    *(uint4*)(dstb + f*64 + ci0) = o;          // coalesced uint4
  }
}

// ---------------------------------------------------------------- K1 (MFMA)
// 128 pixels x 128 out-ch per block; K=128 single pass.
__global__ __launch_bounds__(256) void k1_ln_proj(
    const float* __restrict__ x, const float* __restrict__ g1, const float* __restrict__ b1l,
    const us_t* __restrict__ WpT, const float* __restrict__ bp, us_t* __restrict__ xin)
{
  __shared__ __align__(16) us_t As[128*136];
  __shared__ __align__(16) us_t Ws[128*136];
  __shared__ float gs[128], bs[128];
  int t = threadIdx.x;
  int p0 = blockIdx.x * 128;
  int lane = t & 63, wv = t >> 6;

  if (t < 128){ gs[t] = g1[t]; bs[t] = b1l[t]; }
  #pragma unroll
  for (int i = 0; i < 8; i++){                 // stage WpT -> Ws
    int chunk = i*256 + t;
    int row = chunk >> 4, k0 = (chunk & 15) << 3;
    *(uint4*)&Ws[row*136 + k0] = *(const uint4*)(WpT + row*128 + k0);
  }
  // LN1: 2 lanes per pixel, 64 channels each, register-resident
  int pl = t >> 1, half = t & 1;
  const float* xr = x + (size_t)(p0 + pl)*128 + half*64;
  float xv[64];
  float s = 0.f, q = 0.f;
  #pragma unroll
  for (int i = 0; i < 16; i++){
    float4 d = *(const float4*)(xr + i*4);
    xv[i*4+0] = d.x; xv[i*4+1] = d.y; xv[i*4+2] = d.z; xv[i*4+3] = d.w;
    s += d.x + d.y + d.z + d.w;
    q += d.x*d.x + d.y*d.y + d.z*d.z + d.w*d.w;
  }
  s += __shfl_xor(s, 1, 64);
  q += __shfl_xor(q, 1, 64);
  float m = s*(1.f/128.f);
  float rstd = rsqrtf(q*(1.f/128.f) - m*m + EPSF);
  __syncthreads();                             // gs/bs (and Ws) visible
  {
    int c0 = half << 6;
    us_t* dst = &As[pl*136 + c0];
    #pragma unroll
    for (int jj = 0; jj < 8; jj++){
      float y[8];
      #pragma unroll
      for (int k = 0; k < 8; k++){
        int idx = jj*8 + k;
        y[k] = (xv[idx] - m)*rstd*gs[c0 + idx] + bs[c0 + idx];
      }
      uint4 o;
      o.x = pack2(y[0], y[1]);
      o.y = pack2(y[2], y[3]);
      o.z = pack2(y[4], y[5]);
      o.w = pack2(y[6], y[7]);
      *(uint4*)&dst[jj*8] = o;
    }
  }
  __syncthreads();
  int wm0 = (wv >> 1) * 64, wn0 = (wv & 1) * 64;
  int fr = lane & 15, fq = lane >> 4;
  f32x4 acc[4][4] = {};                        // [mi=ch frag][ni=pix frag]
  #pragma unroll
  for (int sstep = 0; sstep < 4; sstep++){
    int kb = sstep*32 + fq*8;
    bf16x8 a[4], b[4];
    #pragma unroll
    for (int mi = 0; mi < 4; mi++)
      a[mi] = *(const bf16x8*)&Ws[(wm0 + mi*16 + fr)*136 + kb];
    #pragma unroll
    for (int ni = 0; ni < 4; ni++)
      b[ni] = *(const bf16x8*)&As[(wn0 + ni*16 + fr)*136 + kb];
    #pragma unroll
    for (int mi = 0; mi < 4; mi++)
      #pragma unroll
      for (int ni = 0; ni < 4; ni++)
        acc[mi][ni] = __builtin_amdgcn_mfma_f32_16x16x32_bf16(a[mi], b[ni], acc[mi][ni], 0, 0, 0);
  }
  // epilogue: bias + GELU + scatter to xin (4 consecutive channels per lane)
  #pragma unroll
  for (int mi = 0; mi < 4; mi++){
    int ch0 = wm0 + mi*16 + fq*4;
    float4 bb = *(const float4*)(bp + ch0);
    int branch = ch0 >> 6, c = ch0 & 63;
    #pragma unroll
    for (int ni = 0; ni < 4; ni++){
      int p = p0 + wn0 + ni*16 + fr;
      int b_ = p >> 16, rem = p & 65535, h = rem >> 8, w = rem & 255;
      int g = ((h >> 4) << 4) | (w >> 4);
      int nn = ((h & 15) << 4) | (w & 15);
      float v0 = gelu_f(acc[mi][ni][0] + bb.x);
      float v1 = gelu_f(acc[mi][ni][1] + bb.y);
      float v2 = gelu_f(acc[mi][ni][2] + bb.z);
      float v3 = gelu_f(acc[mi][ni][3] + bb.w);
      size_t row = (size_t)branch*512 + (size_t)b_*256 + g;
      *(uint2*)(xin + (row*256 + nn)*64 + c) = make_uint2(pack2(v0,v1), pack2(v2,v3));
    }
  }
}

// ---------------------------------------------------------------- K2 (chunk RC=128, MFMA)
// ROUND-3 STRUCTURE VERBATIM (passed, absmax 0.117) except Bs staging now
// reads pre-transposed W1T with coalesced uint4 loads.
// grid = 512: n = bid>>1, uv = bid&1 (0 = u half f0..191, 1 = v half f192..383)
// Per block: [128 rows x 64 ci] x [64 ci x 192 f] bf16 MFMA.
// Wave tile 32 rows x 192 f: mi=0..1 (16-row frags), ni=0..11 (16-f frags).
__global__ __launch_bounds__(256) void k2_e1(
    const us_t* __restrict__ xin, const us_t* __restrict__ W1T,
    const float* __restrict__ g2, const float* __restrict__ b2l,
    const float* __restrict__ b1v,
    const float* __restrict__ g3, const float* __restrict__ b3l,
    us_t* __restrict__ u_ln, us_t* __restrict__ vout, int r_base)
{
  __shared__ __align__(16) us_t Bs[192*72];   // W1T half: [f][ci]
  __shared__ __align__(16) us_t As[128*72];   // LN2(x):  [r][ci]
  __shared__ __align__(16) float b1s[192];
  __shared__ __align__(16) float g3s[192];
  __shared__ __align__(16) float b3s[192];
  __shared__ __align__(16) float g2s[64];
  __shared__ __align__(16) float b2s[64];
  int t = threadIdx.x;
  int n = blockIdx.x >> 1, uv = blockIdx.x & 1;
  int lane = t & 63, wv = t >> 6;
  int fr = lane & 15, fq = lane >> 4;

  // ---- stage W1T half -> Bs (fully coalesced uint4); bytes identical to
  // round-3's scatter-staged Bs by construction.
  const us_t* wsrc = W1T + (size_t)n*24576 + uv*12288;
  #pragma unroll
  for (int i = 0; i < 6; i++){
    int chunk = i*256 + t;                     // 0..1535
    int f = chunk >> 3, ci0 = (chunk & 7) << 3;
    *(uint4*)&Bs[f*72 + ci0] = *(const uint4*)(wsrc + chunk*8);
  }
  if (t < 48)        *(float4*)&b1s[t*4]       = *(const float4*)(b1v + n*384 + uv*192 + t*4);
  else if (t < 96)   *(float4*)&g3s[(t-48)*4]  = *(const float4*)(g3  + (t-48)*4);
  else if (t < 144)  *(float4*)&b3s[(t-96)*4]  = *(const float4*)(b3l + (t-96)*4);
  else if (t < 160)  *(float4*)&g2s[(t-144)*4] = *(const float4*)(g2  + (t-144)*4);
  else if (t < 176)  *(float4*)&b2s[(t-160)*4] = *(const float4*)(b2l + (t-160)*4);

  // ---- LN2: 2 lanes/row, 32 ch each, register-resident
  int rr = t >> 1, half = t & 1;
  const us_t* xsrc = xin + ((size_t)(r_base + rr)*256 + n)*64 + half*32;
  uint4 d0 = *(const uint4*)(xsrc);
  uint4 d1 = *(const uint4*)(xsrc + 8);
  uint4 d2 = *(const uint4*)(xsrc + 16);
  uint4 d3 = *(const uint4*)(xsrc + 24);
  float xv[32];
  {
    uint4 dd[4] = {d0, d1, d2, d3};
    #pragma unroll
    for (int j = 0; j < 4; j++){
      xv[j*8+0]=lo2f(dd[j].x); xv[j*8+1]=hi2f(dd[j].x);
      xv[j*8+2]=lo2f(dd[j].y); xv[j*8+3]=hi2f(dd[j].y);
      xv[j*8+4]=lo2f(dd[j].z); xv[j*8+5]=hi2f(dd[j].z);
      xv[j*8+6]=lo2f(dd[j].w); xv[j*8+7]=hi2f(dd[j].w);
    }
  }
  float s = 0.f, q = 0.f;
  #pragma unroll
  for (int j = 0; j < 32; j++){ s += xv[j]; q += xv[j]*xv[j]; }
  s += __shfl_xor(s, 1, 64);
  q += __shfl_xor(q, 1, 64);
  float m = s*(1.f/64.f);
  float rstd = rsqrtf(q*(1.f/64.f) - m*m + EPSF);
  __syncthreads();                             // g2s/b2s ready; Bs complete
  {
    int cb = half*32;
    us_t* dst = &As[rr*72 + cb];
    #pragma unroll
    for (int jj = 0; jj < 4; jj++){
      float y[8];
      #pragma unroll
      for (int k = 0; k < 8; k++){
        int idx = cb + jj*8 + k;
        y[k] = (xv[jj*8+k] - m)*rstd*g2s[idx] + b2s[idx];
      }
      uint4 o;
      o.x = pack2(y[0], y[1]);
      o.y = pack2(y[2], y[3]);
      o.z = pack2(y[4], y[5]);
      o.w = pack2(y[6], y[7]);
      *(uint4*)&dst[jj*8] = o;
    }
  }
  __syncthreads();                             // As complete

  // ---- MFMA: wave tile 32 rows x 192 f; K=64 in two 32-steps
  int wr0 = wv*32;
  f32x4 acc[2][12] = {};
  #pragma unroll
  for (int ks = 0; ks < 2; ks++){
    int kb = ks*32 + fq*8;
    bf16x8 a0 = *(const bf16x8*)&As[(wr0 + fr)*72 + kb];
    bf16x8 a1 = *(const bf16x8*)&As[(wr0 + 16 + fr)*72 + kb];
    #pragma unroll
    for (int ni = 0; ni < 12; ni++){
      bf16x8 b = *(const bf16x8*)&Bs[(ni*16 + fr)*72 + kb];
      acc[0][ni] = __builtin_amdgcn_mfma_f32_16x16x32_bf16(a0, b, acc[0][ni], 0, 0, 0);
      acc[1][ni] = __builtin_amdgcn_mfma_f32_16x16x32_bf16(a1, b, acc[1][ni], 0, 0, 0);
    }
  }

  // ---- epilogue: bias + GELU (+ LN3 for u). D row = wr0+mi*16+fq*4+i,
  // col f = ni*16+fr. 16 fr-lanes give 32B-contiguous 2B stores.
  float bsv[12];
  #pragma unroll
  for (int ni = 0; ni < 12; ni++) bsv[ni] = b1s[ni*16 + fr];
  if (uv == 0){
    float g3v[12], b3v[12];
    #pragma unroll
    for (int ni = 0; ni < 12; ni++){ g3v[ni] = g3s[ni*16+fr]; b3v[ni] = b3s[ni*16+fr]; }
    #pragma unroll
    for (int mi = 0; mi < 2; mi++){
      #pragma unroll
      for (int i = 0; i < 4; i++){
        int r = wr0 + mi*16 + fq*4 + i;
        float y[12];
        float ss = 0.f, qq = 0.f;
        #pragma unroll
        for (int ni = 0; ni < 12; ni++){
          float yv = gelu_f(acc[mi][ni][i] + bsv[ni]);
          y[ni] = yv; ss += yv; qq += yv*yv;
        }
        #pragma unroll
        for (int off = 8; off; off >>= 1){ ss += __shfl_xor(ss, off, 64); qq += __shfl_xor(qq, off, 64); }
        float mm = ss*(1.f/192.f);
        float rs = rsqrtf(qq*(1.f/192.f) - mm*mm + EPSF);
        us_t* dst = u_ln + ((size_t)r*256 + n)*192 + fr;
        #pragma unroll
        for (int ni = 0; ni < 12; ni++)
          dst[ni*16] = f2b((y[ni]-mm)*rs*g3v[ni] + b3v[ni]);
      }
    }
  } else {
    #pragma unroll
    for (int mi = 0; mi < 2; mi++){
      #pragma unroll
      for (int i = 0; i < 4; i++){
        int r = wr0 + mi*16 + fq*4 + i;
        us_t* dst = vout + ((size_t)r*256 + n)*192 + fr;
        #pragma unroll
        for (int ni = 0; ni < 12; ni++)
          dst[ni*16] = f2b(gelu_f(acc[mi][ni][i] + bsv[ni]));
      }
    }
  }
}

// ---------------------------------------------------------------- T1 (RC=128)
// u_ln[r][n][c] -> uT[c][r][n], r in [0,128); grid = 128 r x 2 n-halves
__global__ __launch_bounds__(256) void t1_transpose(const us_t* __restrict__ u_ln, us_t* __restrict__ uT){
  __shared__ us_t ls[128*194];
  int t = threadIdx.x;
  int r = blockIdx.x >> 1, n0 = (blockIdx.x & 1) << 7;
  #pragma unroll
  for (int i = 0; i < 12; i++){
    int chunk = i*256 + t;
    int nn = chunk/24, c0 = (chunk - nn*24)*8;
    uint4 d = *(const uint4*)(u_ln + ((size_t)r*256 + n0 + nn)*192 + c0);
    us_t* dst = &ls[nn*194 + c0];
    dst[0] = (us_t)d.x; dst[1] = (us_t)(d.x>>16);
    dst[2] = (us_t)d.y; dst[3] = (us_t)(d.y>>16);
    dst[4] = (us_t)d.z; dst[5] = (us_t)(d.z>>16);
    dst[6] = (us_t)d.w; dst[7] = (us_t)(d.w>>16);
  }
  __syncthreads();
  #pragma unroll
  for (int i = 0; i < 12; i++){
    int chunk = i*256 + t;
    int c = chunk >> 4, nn0 = (chunk & 15) << 3;
    const us_t* sp = &ls[nn0*194 + c];
    uint4 o;
    o.x = (uint_t)sp[0]     | ((uint_t)sp[194]   << 16);
    o.y = (uint_t)sp[2*194] | ((uint_t)sp[3*194] << 16);
    o.z = (uint_t)sp[4*194] | ((uint_t)sp[5*194] << 16);
    o.w = (uint_t)sp[6*194] | ((uint_t)sp[7*194] << 16);
    *(uint4*)(uT + ((size_t)c*128 + r)*256 + n0 + nn0) = o;
  }
}

// ---------------------------------------------------------------- K3 (RC=128, MFMA)
// per-c SGU: S[r][m] = sum_k U[r][k] W[k][m]; 128x256x256 per c, bf16 MFMA.
// grid = 192 c x 2 mt; block tile 128r x 128m; wave = 64x64; BK=64.
__global__ __launch_bounds__(256) void k3_sgu_mfma(
    const us_t* __restrict__ uT, const us_t* __restrict__ WT,
    const float* __restrict__ bsgu, us_t* __restrict__ sT)
{
  __shared__ __align__(16) us_t As[128*72];
  __shared__ __align__(16) us_t Bs[128*72];
  int t = threadIdx.x;
  int c = blockIdx.x >> 1, mt = blockIdx.x & 1;
  int lane = t & 63, wv = t >> 6;
  int wr0 = (wv >> 1) * 64, wm0 = (wv & 1) * 64;
  int fr = lane & 15, fq = lane >> 4;          // frag row / k-quad
  f32x4 acc[4][4] = {};                         // [mi][ni]

  const us_t* aSrc = uT + (size_t)c*128*256;
  const us_t* bSrc = WT + ((size_t)(c*256 + mt*128))*256;

  for (int ks = 0; ks < 256; ks += 64){
    #pragma unroll
    for (int i = 0; i < 4; i++){               // 128 rows x 64 k per array
      int chunk = i*256 + t;
      int rr = chunk >> 3, kk = (chunk & 7) << 3;
      *(uint4*)&As[rr*72 + kk] = *(const uint4*)(aSrc + rr*256 + ks + kk);
      *(uint4*)&Bs[rr*72 + kk] = *(const uint4*)(bSrc + rr*256 + ks + kk);
    }
    __syncthreads();
    #pragma unroll
    for (int s = 0; s < 2; s++){
      int kb = s*32 + fq*8;
      bf16x8 a[4], b[4];
      #pragma unroll
      for (int mi = 0; mi < 4; mi++)
        a[mi] = *(const bf16x8*)&As[(wr0 + mi*16 + fr)*72 + kb];
      #pragma unroll
      for (int ni = 0; ni < 4; ni++)
        b[ni] = *(const bf16x8*)&Bs[(wm0 + ni*16 + fr)*72 + kb];
      #pragma unroll
      for (int mi = 0; mi < 4; mi++)
        #pragma unroll
        for (int ni = 0; ni < 4; ni++)
          acc[mi][ni] = __builtin_amdgcn_mfma_f32_16x16x32_bf16(a[mi], b[ni], acc[mi][ni], 0, 0, 0);
    }
    __syncthreads();
  }
  // epilogue: D[row=wr0+mi*16+fq*4+i][col=wm0+ni*16+fr] + bsgu[c][m]
  float bsv[4];
  #pragma unroll
  for (int ni = 0; ni < 4; ni++)
    bsv[ni] = bsgu[c*256 + mt*128 + wm0 + ni*16 + fr];
  #pragma unroll
  for (int mi = 0; mi < 4; mi++){
    #pragma unroll
    for (int i = 0; i < 4; i++){
      int r = wr0 + mi*16 + fq*4 + i;          // 0..127
      us_t* dst = sT + ((size_t)c*128 + r)*256 + mt*128 + wm0 + fr;
      #pragma unroll
      for (int ni = 0; ni < 4; ni++)
        dst[ni*16] = f2b(acc[mi][ni][i] + bsv[ni]);
    }
  }
}

// ---------------------------------------------------------------- T2 (RC=128)
// t[r][m][c] = sT[c][r][m] * v[r][m][c], r in [0,128)
__global__ __launch_bounds__(256) void t2_mul(
    const us_t* __restrict__ sT, const us_t* __restrict__ v, us_t* __restrict__ tout)
{
  __shared__ us_t ls[192*130];
  int t = threadIdx.x;
  int r = blockIdx.x >> 1, m0 = (blockIdx.x & 1) << 7;
  #pragma unroll
  for (int i = 0; i < 12; i++){
    int chunk = i*256 + t;
    int c = chunk >> 4, mm0 = (chunk & 15) << 3;
    uint4 d = *(const uint4*)(sT + ((size_t)c*128 + r)*256 + m0 + mm0);
    us_t* dst = &ls[c*130 + mm0];
    dst[0] = (us_t)d.x; dst[1] = (us_t)(d.x>>16);
    dst[2] = (us_t)d.y; dst[3] = (us_t)(d.y>>16);
    dst[4] = (us_t)d.z; dst[5] = (us_t)(d.z>>16);
    dst[6] = (us_t)d.w; dst[7] = (us_t)(d.w>>16);
  }
  __syncthreads();
  #pragma unroll
  for (int i = 0; i < 12; i++){
    int chunk = i*256 + t;
    int mm = chunk/24, c0 = (chunk - mm*24)*8;
    size_t gidx = ((size_t)r*256 + m0 + mm)*192 + c0;
    uint4 vv = *(const uint4*)(v + gidx);
    const us_t* sp = &ls[c0*130 + mm];
    uint4 o;
    o.x = pack2(b2f(sp[0])*lo2f(vv.x),     b2f(sp[130])*hi2f(vv.x));
    o.y = pack2(b2f(sp[2*130])*lo2f(vv.y), b2f(sp[3*130])*hi2f(vv.y));
    o.z = pack2(b2f(sp[4*130])*lo2f(vv.z), b2f(sp[5*130])*hi2f(vv.z));
    o.w = pack2(b2f(sp[6*130])*lo2f(vv.w), b2f(sp[7*130])*hi2f(vv.w));
    *(uint4*)(tout + gidx) = o;
  }
}

// ---------------------------------------------------------------- K4 (RC=128)
// grid = 256 n x 2 rt
__global__ __launch_bounds__(256) void k4_out(
    const us_t* __restrict__ tbuf, const float* __restrict__ W2,
    const float* __restrict__ b2v, const us_t* __restrict__ xin,
    const float* __restrict__ x, float* __restrict__ out0, float* __restrict__ out1,
    int r_base)
{
  __shared__ __align__(16) us_t W2s[192*64];
  __shared__ __align__(16) us_t ts[192*68];   // [f][row]
  int t = threadIdx.x;
  int n = blockIdx.x >> 1, rt = blockIdx.x & 1;
  const float* wsrc = W2 + (size_t)n*12288;
  #pragma unroll
  for (int i = 0; i < 12; i++){   // W2 fp32 -> bf16 LDS
    int idx = (i*256 + t)*4;
    float4 w = *(const float4*)(wsrc + idx);
    *(uint2*)&W2s[idx] = make_uint2(pack2(w.x,w.y), pack2(w.z,w.w));
  }
  #pragma unroll
  for (int i = 0; i < 6; i++){
    int chunk = i*256 + t;
    int rr = chunk/24, ff0 = (chunk - rr*24)*8;
    uint4 d = *(const uint4*)(tbuf + ((size_t)(rt*64 + rr)*256 + n)*192 + ff0);
    us_t* dst = &ts[ff0*68 + rr];
    dst[0]    = (us_t)d.x; dst[68]   = (us_t)(d.x>>16);
    dst[2*68] = (us_t)d.y; dst[3*68] = (us_t)(d.y>>16);
    dst[4*68] = (us_t)d.z; dst[5*68] = (us_t)(d.z>>16);
    dst[6*68] = (us_t)d.w; dst[7*68] = (us_t)(d.w>>16);
  }
  __syncthreads();
  int cg = t & 15, rg = t >> 4;
  int c0 = cg*4, rr0 = rg*4;
  float acc[4][4] = {};
  #pragma unroll 4
  for (int f = 0; f < 192; f++){
    uint2 au = *(const uint2*)&ts[f*68 + rr0];
    uint2 wu = *(const uint2*)&W2s[f*64 + c0];
    float a0 = lo2f(au.x), a1 = hi2f(au.x), a2 = lo2f(au.y), a3 = hi2f(au.y);
    float w0 = lo2f(wu.x), w1 = hi2f(wu.x), w2 = lo2f(wu.y), w3 = hi2f(wu.y);
    acc[0][0] += a0*w0; acc[0][1] += a0*w1; acc[0][2] += a0*w2; acc[0][3] += a0*w3;
    acc[1][0] += a1*w0; acc[1][1] += a1*w1; acc[1][2] += a1*w2; acc[1][3] += a1*w3;
    acc[2][0] += a2*w0; acc[2][1] += a2*w1; acc[2][2] += a2*w2; acc[2][3] += a2*w3;
    acc[3][0] += a3*w0; acc[3][1] += a3*w1; acc[3][2] += a3*w2; acc[3][3] += a3*w3;
  }
  float4 bb = *(const float4*)(b2v + n*64 + c0);
  #pragma unroll
  for (int i = 0; i < 4; i++){
    int rl = rt*64 + rr0 + i;                  // chunk-local 0..127
    int r = r_base + rl;                       // global row
    int branch = r >> 9, bidx = (r >> 8) & 1, g = r & 255;
    uint2 xi = *(const uint2*)(xin + ((size_t)r*256 + n)*64 + c0);
    float v0 = acc[i][0] + bb.x + lo2f(xi.x);
    float v1 = acc[i][1] + bb.y + hi2f(xi.x);
    float v2 = acc[i][2] + bb.z + lo2f(xi.y);
    float v3 = acc[i][3] + bb.w + hi2f(xi.y);
    int h, w;
    if (branch == 0){ h = ((n >> 4) << 4) | (g >> 4); w = ((n & 15) << 4) | (g & 15); }
    else            { h = ((g >> 4) << 4) | (n >> 4); w = ((g & 15) << 4) | (n & 15); }
    size_t base = (size_t)(bidx*256 + h)*256 + w;
    size_t o0idx = base*128 + (branch << 6) + c0;
    float4 xr = *(const float4*)(x + o0idx);
    *(float4*)(out0 + o0idx) = make_float4(v0 + xr.x, v1 + xr.y, v2 + xr.z, v3 + xr.w);
    if (branch){
      *(float4*)(out1 + base*64 + c0) = make_float4(v0, v1, v2, v3);
    }
  }
}

// ---------------------------------------------------------------- launch
extern "C" void kernel_launch(void* const* d_in, const int* in_sizes, int n_in,
                              void* d_out, int out_size, void* d_ws, size_t ws_size,
                              hipStream_t stream)
{
  (void)in_sizes; (void)n_in; (void)out_size;
  const float* x    = (const float*)d_in[0];
  const float* g1   = (const float*)d_in[1];
  const float* b1l  = (const float*)d_in[2];
  const float* Wp   = (const float*)d_in[3];
  const float* bp   = (const float*)d_in[4];
  const float* g2   = (const float*)d_in[5];
  const float* b2l  = (const float*)d_in[6];
  const float* W1   = (const float*)d_in[7];
  const float* b1v  = (const float*)d_in[8];
  const float* g3   = (const float*)d_in[9];
  const float* b3l  = (const float*)d_in[10];
  const float* Wsgu = (const float*)d_in[11];
  const float* bsgu = (const float*)d_in[12];
  const float* W2   = (const float*)d_in[13];
  const float* b2v  = (const float*)d_in[14];

  float* out0 = (float*)d_out;
  float* out1 = out0 + (size_t)2*256*256*128;

  us_t* ws   = (us_t*)d_ws;
  us_t* xin  = ws;                       // [1024][256][64]        16,777,216
  us_t* bufA = ws + 16777216;            // u_ln -> sT (chunk)      6,291,456
  us_t* bufV = bufA + 6291456;           // v (chunk)               6,291,456
  us_t* bufB = bufV + 6291456;           // uT -> t (chunk)         6,291,456
  us_t* WT   = bufB + 6291456;           // Wsgu^T bf16 [c][m][k]  12,582,912
  us_t* WpT  = WT + 12582912;            // Wp^T bf16 [out][in]        16,384

  // W1T bf16 [n][384f][64ci]: dedicated region if ws has room, else reuse
  // bufB (dead during k2) and re-transpose each chunk.
  bool dedicated = ws_size >= 109084672ULL;
  us_t* W1T = dedicated ? (WpT + 16384) : bufB;

  wprep      <<<dim3(769),  dim3(256), 0, stream>>>(Wsgu, Wp, WT, WpT);
  if (dedicated)
    w1t      <<<dim3(256),  dim3(256), 0, stream>>>(W1, W1T);
  k1_ln_proj <<<dim3(1024), dim3(256), 0, stream>>>(x, g1, b1l, WpT, bp, xin);
  for (int chunk = 0; chunk < 8; ++chunk){
    int r_base = chunk * 128;
    if (!dedicated)
      w1t       <<<dim3(256),  dim3(256), 0, stream>>>(W1, W1T);
    k2_e1       <<<dim3(512),  dim3(256), 0, stream>>>(xin, W1T, g2, b2l, b1v, g3, b3l, bufA, bufV, r_base);
    t1_transpose<<<dim3(256),  dim3(256), 0, stream>>>(bufA, bufB);
    k3_sgu_mfma <<<dim3(384),  dim3(256), 0, stream>>>(bufB, WT, bsgu, bufA);
    t2_mul      <<<dim3(256),  dim3(256), 0, stream>>>(bufA, bufV, bufB);
    k4_out      <<<dim3(512),  dim3(256), 0, stream>>>(bufB, W2, b2v, xin, x, out0, out1, r_base);
  }
}